// Round 3
// baseline (49.333 us; speedup 1.0000x reference)
//
#include <hip/hip_runtime.h>

#define PAGE_SIZE 16

// Native clang vector type — __builtin_nontemporal_* requires a vector of
// scalar types, not HIP_vector_type structs.
typedef float f4 __attribute__((ext_vector_type(4)));

// One block per appended token. Each thread moves one float4 of the K row
// and one float4 of the V row into the paged cache. Streaming (nontemporal)
// on both sides: no reuse anywhere, so don't let stores thrash L2/L3.
__global__ __launch_bounds__(256) void kv_append_kernel(
    const f4* __restrict__ k,
    const f4* __restrict__ v,
    f4* __restrict__ out,
    const int* __restrict__ kv_append_indptr,
    const int* __restrict__ paged_kv_indptr,
    const int* __restrict__ paged_kv_indices,
    const int* __restrict__ last_page_len,
    int B, int nnz, int row_f4)
{
    int token = blockIdx.x;
    if (token >= nnz) return;

    // searchsorted(kv_append_indptr, token, side="right") - 1
    int b = B - 1;
    for (int i = 1; i < B; ++i) {
        if (token < kv_append_indptr[i]) { b = i - 1; break; }
    }
    int local      = token - kv_append_indptr[b];
    int np         = paged_kv_indptr[b + 1] - paged_kv_indptr[b];
    int seq_len    = (np > 0) ? ((np - 1) * PAGE_SIZE + last_page_len[b]) : 0;
    int append_len = kv_append_indptr[b + 1] - kv_append_indptr[b];
    int pos        = seq_len - append_len + local;            // >= 0 by construction
    int page_iter  = paged_kv_indptr[b] + pos / PAGE_SIZE;
    int page_id    = paged_kv_indices[page_iter];
    int off        = pos % PAGE_SIZE;

    size_t srow  = (size_t)token * row_f4;
    size_t drowk = ((size_t)page_id * 2 * PAGE_SIZE + off) * (size_t)row_f4;
    size_t drowv = drowk + (size_t)PAGE_SIZE * row_f4;

    for (int c = threadIdx.x; c < row_f4; c += blockDim.x) {
        f4 kv4 = __builtin_nontemporal_load(&k[srow + c]);
        f4 vv4 = __builtin_nontemporal_load(&v[srow + c]);
        __builtin_nontemporal_store(kv4, &out[drowk + c]);
        __builtin_nontemporal_store(vv4, &out[drowv + c]);
    }
}

extern "C" void kernel_launch(void* const* d_in, const int* in_sizes, int n_in,
                              void* d_out, int out_size, void* d_ws, size_t ws_size,
                              hipStream_t stream)
{
    const f4* k = (const f4*)d_in[0];
    const f4* v = (const f4*)d_in[1];
    // d_in[2] = kv_cache (zeros; fully overwritten by the scatter -> unused)
    const int* kv_append_indptr      = (const int*)d_in[3];
    const int* paged_kv_indptr       = (const int*)d_in[4];
    const int* paged_kv_indices      = (const int*)d_in[5];
    const int* paged_kv_last_page_len = (const int*)d_in[6];

    int B       = in_sizes[3] - 1;
    int n_pages = in_sizes[5];
    int HD      = in_sizes[2] / (n_pages * 2 * PAGE_SIZE);   // = H*D = 1024
    int row_f4  = HD / 4;                                    // = 256
    int nnz     = in_sizes[0] / HD;                          // = 16384

    dim3 grid(nnz), block(256);
    kv_append_kernel<<<grid, block, 0, stream>>>(
        k, v, (f4*)d_out,
        kv_append_indptr, paged_kv_indptr, paged_kv_indices,
        paged_kv_last_page_len, B, nnz, row_f4);
}

// Round 4
// 45.933 us; speedup vs baseline: 1.0740x; 1.0740x over previous
//
#include <hip/hip_runtime.h>

#define PAGE_SIZE 16

// Native clang vector type — __builtin_nontemporal_* requires a vector of
// scalar types, not HIP_vector_type structs.
typedef float f4 __attribute__((ext_vector_type(4)));

// One block per appended token. Each thread moves one float4 of the K row
// and one float4 of the V row into the paged cache.
// Policy split (R3): NORMAL loads — k/v are partially L3-resident across
// graph replays (R1: FETCH=64MiB of 128MiB logical) and nt loads killed
// those hits (R2 regression). NONTEMPORAL stores — the 128MiB of written
// cache is never re-read in-kernel; skipping write-allocate leaves L3 room
// for the input stream.
__global__ __launch_bounds__(256) void kv_append_kernel(
    const f4* __restrict__ k,
    const f4* __restrict__ v,
    f4* __restrict__ out,
    const int* __restrict__ kv_append_indptr,
    const int* __restrict__ paged_kv_indptr,
    const int* __restrict__ paged_kv_indices,
    const int* __restrict__ last_page_len,
    int B, int nnz, int row_f4)
{
    int token = blockIdx.x;
    if (token >= nnz) return;

    // searchsorted(kv_append_indptr, token, side="right") - 1
    int b = B - 1;
    for (int i = 1; i < B; ++i) {
        if (token < kv_append_indptr[i]) { b = i - 1; break; }
    }
    int local      = token - kv_append_indptr[b];
    int np         = paged_kv_indptr[b + 1] - paged_kv_indptr[b];
    int seq_len    = (np > 0) ? ((np - 1) * PAGE_SIZE + last_page_len[b]) : 0;
    int append_len = kv_append_indptr[b + 1] - kv_append_indptr[b];
    int pos        = seq_len - append_len + local;            // >= 0 by construction
    int page_iter  = paged_kv_indptr[b] + pos / PAGE_SIZE;
    int page_id    = paged_kv_indices[page_iter];
    int off        = pos % PAGE_SIZE;

    size_t srow  = (size_t)token * row_f4;
    size_t drowk = ((size_t)page_id * 2 * PAGE_SIZE + off) * (size_t)row_f4;
    size_t drowv = drowk + (size_t)PAGE_SIZE * row_f4;

    for (int c = threadIdx.x; c < row_f4; c += blockDim.x) {
        f4 kv4 = k[srow + c];          // normal load: keep L3 hits
        f4 vv4 = v[srow + c];
        __builtin_nontemporal_store(kv4, &out[drowk + c]);   // stream write
        __builtin_nontemporal_store(vv4, &out[drowv + c]);
    }
}

extern "C" void kernel_launch(void* const* d_in, const int* in_sizes, int n_in,
                              void* d_out, int out_size, void* d_ws, size_t ws_size,
                              hipStream_t stream)
{
    const f4* k = (const f4*)d_in[0];
    const f4* v = (const f4*)d_in[1];
    // d_in[2] = kv_cache (zeros; fully overwritten by the scatter -> unused)
    const int* kv_append_indptr      = (const int*)d_in[3];
    const int* paged_kv_indptr       = (const int*)d_in[4];
    const int* paged_kv_indices      = (const int*)d_in[5];
    const int* paged_kv_last_page_len = (const int*)d_in[6];

    int B       = in_sizes[3] - 1;
    int n_pages = in_sizes[5];
    int HD      = in_sizes[2] / (n_pages * 2 * PAGE_SIZE);   // = H*D = 1024
    int row_f4  = HD / 4;                                    // = 256
    int nnz     = in_sizes[0] / HD;                          // = 16384

    dim3 grid(nnz), block(256);
    kv_append_kernel<<<grid, block, 0, stream>>>(
        k, v, (f4*)d_out,
        kv_append_indptr, paged_kv_indptr, paged_kv_indices,
        paged_kv_last_page_len, B, nnz, row_f4);
}